// Round 3
// baseline (1060.793 us; speedup 1.0000x reference)
//
#include <hip/hip_runtime.h>
#include <hip/hip_cooperative_groups.h>
#include <cmath>

namespace cg = cooperative_groups;

#define NNODES 4096
#define FDIM 512
#define DH 64
#define CAP 128
#define NBLK 256
#define NTHR 1024          // 16 waves/block, 1 block/CU, 4096 waves total

struct Params {
    const float *adj, *feat;
    const float *W0, *al0, *ar0, *b0;
    const float *W1, *al1, *ar1, *b1;
    const float *W2, *al2, *ar2, *b2;
    float* out;
    int* nbr; int* deg;
    float* x; float* el; float* er; float* hbuf;
};

// ---------------------------------------------------------------------------
// Stage A: grid-stride scan of dense adjacency (64 MB, fully coalesced),
// compacting nonzero columns via global atomics on deg[row] (~131K total,
// ~32 per address — negligible contention). Slot order arbitrary (sums are
// order-independent inside fp32 noise; validated: absmax 2e-3 vs 1.6e-2).
// ---------------------------------------------------------------------------
__device__ void build_stage(const float* __restrict__ adj,
                            int* __restrict__ nbr, int* __restrict__ deg)
{
    const int gtid = blockIdx.x * NTHR + threadIdx.x;
    const int stride = NBLK * NTHR;                 // 262144
    const float4* adj4 = reinterpret_cast<const float4*>(adj);
    const int total = NNODES * NNODES / 4;          // 4,194,304 -> 16 iters
    for (int i = gtid; i < total; i += stride) {
        float4 v = adj4[i];
        int row = i >> 10;                          // 1024 float4 per row
        int base = (i & 1023) << 2;
        if (v.x != 0.f) { int p = atomicAdd(&deg[row], 1); if (p < CAP) nbr[row * CAP + p] = base + 0; }
        if (v.y != 0.f) { int p = atomicAdd(&deg[row], 1); if (p < CAP) nbr[row * CAP + p] = base + 1; }
        if (v.z != 0.f) { int p = atomicAdd(&deg[row], 1); if (p < CAP) nbr[row * CAP + p] = base + 2; }
        if (v.w != 0.f) { int p = atomicAdd(&deg[row], 1); if (p < CAP) nbr[row * CAP + p] = base + 3; }
    }
}

// ---------------------------------------------------------------------------
// Stage B: x = h@W, el = x@al, er = x@ar.
// 16 waves/block = 4 node-groups x 4 K-quarter waves; LDS partial reduce;
// wave (g,kq) finalizes node g*4+kq incl. 8-head shuffle reductions.
// W-quarter per wave = 32 KB -> total W L2 traffic 128 MB (~4 us).
// ---------------------------------------------------------------------------
template <int H>
__device__ void mm_proj_stage(const float* __restrict__ h, const float* __restrict__ W,
                              const float* __restrict__ al, const float* __restrict__ ar,
                              float* __restrict__ x, float* __restrict__ el,
                              float* __restrict__ er, float (*part)[4][4][DH])
{
    const int lane = threadIdx.x & 63;
    const int wv = threadIdx.x >> 6;   // 0..15
    const int g = wv >> 2;             // node-group
    const int kq = wv & 3;             // K-quarter
    const int r0 = blockIdx.x * 16 + g * 4;

    float acc[4] = {0.f, 0.f, 0.f, 0.f};
    const int k0 = kq * (FDIM / 4);
    for (int k = k0; k < k0 + FDIM / 4; k += 4) {
        float w0 = W[(k + 0) * DH + lane];
        float w1 = W[(k + 1) * DH + lane];
        float w2 = W[(k + 2) * DH + lane];
        float w3 = W[(k + 3) * DH + lane];
#pragma unroll
        for (int r = 0; r < 4; r++) {
            float4 a = *reinterpret_cast<const float4*>(h + (size_t)(r0 + r) * FDIM + k);
            acc[r] = fmaf(a.x, w0, fmaf(a.y, w1, fmaf(a.z, w2, fmaf(a.w, w3, acc[r]))));
        }
    }
#pragma unroll
    for (int r = 0; r < 4; r++) part[g][kq][r][lane] = acc[r];
    __syncthreads();

    float xv = part[g][0][kq][lane] + part[g][1][kq][lane]
             + part[g][2][kq][lane] + part[g][3][kq][lane];
    const int node = r0 + kq;
    x[(size_t)node * DH + lane] = xv;
#pragma unroll
    for (int hh = 0; hh < H; hh++) {
        float vl = xv * al[lane * H + hh];
        float vr = xv * ar[lane * H + hh];
#pragma unroll
        for (int off = 32; off >= 1; off >>= 1) {
            vl += __shfl_xor(vl, off, 64);
            vr += __shfl_xor(vr, off, 64);
        }
        if (lane == 0) {
            el[node * H + hh] = vl;
            er[node * H + hh] = vr;
        }
    }
}

// ---------------------------------------------------------------------------
// Stage C: sparse GAT aggregate. Wave per (node, head-group) task, lane =
// output dim; x2-unrolled neighbor loop keeps two scattered loads in flight.
// ---------------------------------------------------------------------------
template <int H, int GPN, bool ACT>
__device__ void aggregate_stage(const float* __restrict__ x, const float* __restrict__ el,
                                const float* __restrict__ er, const int* __restrict__ nbr,
                                const int* __restrict__ deg, const float* __restrict__ bias,
                                float* __restrict__ out)
{
    constexpr int HPG = H / GPN;
    const int lane = threadIdx.x & 63;
    const int wv = threadIdx.x >> 6;
    const int wgid = blockIdx.x * 16 + wv;          // 0..4095
    const int ntask = NNODES * GPN;
    const float bv = bias[lane];

    for (int t = wgid; t < ntask; t += NBLK * 16) {
        const int node = t / GPN;
        const int h0 = (t % GPN) * HPG;
        float eli[HPG], acc[HPG], den[HPG];
#pragma unroll
        for (int hh = 0; hh < HPG; hh++) {
            eli[hh] = el[node * H + h0 + hh];
            acc[hh] = 0.f;
            den[hh] = 0.f;
        }
        int dg = deg[node]; dg = dg < CAP ? dg : CAP;
        const int* nb = nbr + (size_t)node * CAP;

        int k = 0;
        for (; k + 2 <= dg; k += 2) {
            int j0 = nb[k], j1 = nb[k + 1];
            float xv0 = x[(size_t)j0 * DH + lane];
            float xv1 = x[(size_t)j1 * DH + lane];
            float e0[HPG], e1[HPG];
#pragma unroll
            for (int hh = 0; hh < HPG; hh++) {
                e0[hh] = er[j0 * H + h0 + hh];
                e1[hh] = er[j1 * H + h0 + hh];
            }
#pragma unroll
            for (int hh = 0; hh < HPG; hh++) {
                float s0 = eli[hh] + e0[hh];
                float s1 = eli[hh] + e1[hh];
                s0 = s0 > 0.f ? s0 : 0.2f * s0;
                s1 = s1 > 0.f ? s1 : 0.2f * s1;
                float w0 = __expf(s0), w1 = __expf(s1);
                acc[hh] = fmaf(w0, xv0, acc[hh]);
                acc[hh] = fmaf(w1, xv1, acc[hh]);
                den[hh] += w0 + w1;
            }
        }
        if (k < dg) {
            int j = nb[k];
            float xv = x[(size_t)j * DH + lane];
#pragma unroll
            for (int hh = 0; hh < HPG; hh++) {
                float s = eli[hh] + er[j * H + h0 + hh];
                s = s > 0.f ? s : 0.2f * s;
                float w = __expf(s);
                acc[hh] = fmaf(w, xv, acc[hh]);
                den[hh] += w;
            }
        }
#pragma unroll
        for (int hh = 0; hh < HPG; hh++) {
            float o = acc[hh] / fmaxf(den[hh], 1e-12f) + bv;
            if (ACT) o = o > 0.f ? o : __expf(o) - 1.f;   // elu
            out[(size_t)node * (H * DH) + (h0 + hh) * DH + lane] = o;
        }
    }
}

// ---------------------------------------------------------------------------
// The whole 3-layer GAT in ONE cooperative kernel: 8 grid.sync()s replace
// 6 inter-kernel launch overheads (the R1->R2 delta showed ~10 us/launch).
// ---------------------------------------------------------------------------
__global__ __launch_bounds__(NTHR, 4) void gat_fused(Params p)
{
    __shared__ float part[4][4][4][DH];   // 16 KB
    cg::grid_group grid = cg::this_grid();

    // zero deg (ws is poisoned 0xAA every replay)
    const int gtid = blockIdx.x * NTHR + threadIdx.x;
    if (gtid < NNODES) p.deg[gtid] = 0;
    __threadfence();
    grid.sync();

    build_stage(p.adj, p.nbr, p.deg);
    __threadfence();
    grid.sync();

    // layer 0
    mm_proj_stage<8>(p.feat, p.W0, p.al0, p.ar0, p.x, p.el, p.er, part);
    __threadfence();
    grid.sync();
    aggregate_stage<8, 2, true>(p.x, p.el, p.er, p.nbr, p.deg, p.b0, p.hbuf);
    __threadfence();
    grid.sync();

    // layer 1
    mm_proj_stage<8>(p.hbuf, p.W1, p.al1, p.ar1, p.x, p.el, p.er, part);
    __threadfence();
    grid.sync();
    aggregate_stage<8, 2, true>(p.x, p.el, p.er, p.nbr, p.deg, p.b1, p.hbuf);
    __threadfence();
    grid.sync();

    // layer 2 (1 head, no activation) -> out
    mm_proj_stage<1>(p.hbuf, p.W2, p.al2, p.ar2, p.x, p.el, p.er, part);
    __threadfence();
    grid.sync();
    aggregate_stage<1, 1, false>(p.x, p.el, p.er, p.nbr, p.deg, p.b2, p.out);
}

// ---------------------------------------------------------------------------
extern "C" void kernel_launch(void* const* d_in, const int* in_sizes, int n_in,
                              void* d_out, int out_size, void* d_ws, size_t ws_size,
                              hipStream_t stream)
{
    Params p;
    p.adj  = (const float*)d_in[0];
    p.feat = (const float*)d_in[1];
    p.W0 = (const float*)d_in[2];  p.al0 = (const float*)d_in[3];
    p.ar0 = (const float*)d_in[4]; p.b0  = (const float*)d_in[5];
    p.W1 = (const float*)d_in[6];  p.al1 = (const float*)d_in[7];
    p.ar1 = (const float*)d_in[8]; p.b1  = (const float*)d_in[9];
    p.W2 = (const float*)d_in[10]; p.al2 = (const float*)d_in[11];
    p.ar2 = (const float*)d_in[12]; p.b2 = (const float*)d_in[13];
    p.out = (float*)d_out;

    char* ws = (char*)d_ws;
    p.nbr  = (int*)ws;   ws += (size_t)NNODES * CAP * sizeof(int);    // 2 MB
    p.deg  = (int*)ws;   ws += (size_t)NNODES * sizeof(int);          // 16 KB
    p.x    = (float*)ws; ws += (size_t)NNODES * DH * sizeof(float);   // 1 MB
    p.el   = (float*)ws; ws += (size_t)NNODES * 8 * sizeof(float);    // 128 KB
    p.er   = (float*)ws; ws += (size_t)NNODES * 8 * sizeof(float);    // 128 KB
    p.hbuf = (float*)ws; ws += (size_t)NNODES * FDIM * sizeof(float); // 8 MB

    void* args[] = {&p};
    hipLaunchCooperativeKernel((const void*)gat_fused, dim3(NBLK), dim3(NTHR),
                               args, 0, stream);
}

// Round 4
// 235.183 us; speedup vs baseline: 4.5105x; 4.5105x over previous
//
#include <hip/hip_runtime.h>
#include <cmath>

#define NNODES 4096
#define FDIM 512
#define DH 64
#define CAP 128

// ---------------------------------------------------------------------------
// Kernel 1 (heterogeneous): blocks [0,4096) build neighbor lists from the
// dense adjacency (one block per row, 64 MB coalesced read — the HBM floor);
// blocks [4096,5120) run layer-0 mm+proj (independent of build).
// ---------------------------------------------------------------------------
__global__ __launch_bounds__(256) void k_build_mm0(
    const float* __restrict__ adj, int* __restrict__ nbr, int* __restrict__ deg,
    const float* __restrict__ feat, const float* __restrict__ W0,
    const float* __restrict__ al0, const float* __restrict__ ar0,
    float* __restrict__ x, float* __restrict__ el, float* __restrict__ er)
{
    __shared__ float part[4][4][DH];   // mm role: 4 KB
    __shared__ int cnt;                // build role

    if (blockIdx.x < NNODES) {
        // ---- build role: compact nonzeros of one adjacency row
        const int row = blockIdx.x;
        if (threadIdx.x == 0) cnt = 0;
        __syncthreads();
        const float4* arow = reinterpret_cast<const float4*>(adj + (size_t)row * NNODES);
        int* nrow = nbr + (size_t)row * CAP;
        for (int c4 = threadIdx.x; c4 < NNODES / 4; c4 += 256) {
            float4 v = arow[c4];
            int base = c4 * 4;
            if (v.x != 0.f) { int p = atomicAdd(&cnt, 1); if (p < CAP) nrow[p] = base + 0; }
            if (v.y != 0.f) { int p = atomicAdd(&cnt, 1); if (p < CAP) nrow[p] = base + 1; }
            if (v.z != 0.f) { int p = atomicAdd(&cnt, 1); if (p < CAP) nrow[p] = base + 2; }
            if (v.w != 0.f) { int p = atomicAdd(&cnt, 1); if (p < CAP) nrow[p] = base + 3; }
        }
        __syncthreads();
        if (threadIdx.x == 0) deg[row] = cnt < CAP ? cnt : CAP;
        return;
    }

    // ---- mm0+proj0 role: 4 nodes per block, wave = K-quarter
    const int lane = threadIdx.x & 63;
    const int kq = threadIdx.x >> 6;                 // 0..3
    const int r0 = (blockIdx.x - NNODES) * 4;

    float acc[4] = {0.f, 0.f, 0.f, 0.f};
    const int k0 = kq * (FDIM / 4);
    for (int k = k0; k < k0 + FDIM / 4; k += 4) {
        float w0 = W0[(k + 0) * DH + lane];
        float w1 = W0[(k + 1) * DH + lane];
        float w2 = W0[(k + 2) * DH + lane];
        float w3 = W0[(k + 3) * DH + lane];
#pragma unroll
        for (int r = 0; r < 4; r++) {
            float4 a = *reinterpret_cast<const float4*>(feat + (size_t)(r0 + r) * FDIM + k);
            acc[r] = fmaf(a.x, w0, fmaf(a.y, w1, fmaf(a.z, w2, fmaf(a.w, w3, acc[r]))));
        }
    }
#pragma unroll
    for (int r = 0; r < 4; r++) part[kq][r][lane] = acc[r];
    __syncthreads();

    float xv = part[0][kq][lane] + part[1][kq][lane] + part[2][kq][lane] + part[3][kq][lane];
    const int node = r0 + kq;
    x[(size_t)node * DH + lane] = xv;
#pragma unroll
    for (int hh = 0; hh < 8; hh++) {
        float vl = xv * al0[lane * 8 + hh];
        float vr = xv * ar0[lane * 8 + hh];
#pragma unroll
        for (int off = 32; off >= 1; off >>= 1) {
            vl += __shfl_xor(vl, off, 64);
            vr += __shfl_xor(vr, off, 64);
        }
        if (lane == 0) {
            el[node * 8 + hh] = vl;
            er[node * 8 + hh] = vr;
        }
    }
}

// ---------------------------------------------------------------------------
// Kernel 2/3 (fused agg_L + mm_{L+1} + proj): block owns 8 nodes.
// Phase A: 8-head GAT aggregate for those nodes -> LDS h_s[8][512] (never
//   touches global hbuf). 16 tasks (node x head-half) over 8 waves.
// Phase B: x_out = h_s @ W (K from LDS broadcast reads), then el/er proj.
// x/el/er double-buffered across launches (other blocks still read layer L).
// ---------------------------------------------------------------------------
template <int PROJ_H>
__global__ __launch_bounds__(512) void k_agg_mm(
    const float* __restrict__ x_in, const float* __restrict__ el_in,
    const float* __restrict__ er_in, const int* __restrict__ nbr,
    const int* __restrict__ deg, const float* __restrict__ bias_agg,
    const float* __restrict__ W, const float* __restrict__ al,
    const float* __restrict__ ar, float* __restrict__ x_out,
    float* __restrict__ el_out, float* __restrict__ er_out)
{
    __shared__ float h_s[8][FDIM];        // 16 KB
    __shared__ float part[2][4][4][DH];   // 8 KB
    const int lane = threadIdx.x & 63;
    const int wv = threadIdx.x >> 6;      // 0..7
    const int n0 = blockIdx.x * 8;
    const float bv = bias_agg[lane];

    // ---- Phase A: aggregate (H=8, 2 head-halves per node)
    for (int t = wv; t < 16; t += 8) {
        const int node = n0 + (t >> 1);
        const int h0 = (t & 1) * 4;
        float eli[4], acc[4], den[4];
#pragma unroll
        for (int hh = 0; hh < 4; hh++) {
            eli[hh] = el_in[node * 8 + h0 + hh];
            acc[hh] = 0.f;
            den[hh] = 0.f;
        }
        const int dg = deg[node];
        const int* nb = nbr + (size_t)node * CAP;
        int k = 0;
        for (; k + 2 <= dg; k += 2) {
            int j0 = nb[k], j1 = nb[k + 1];
            float xv0 = x_in[(size_t)j0 * DH + lane];
            float xv1 = x_in[(size_t)j1 * DH + lane];
            float e0[4], e1[4];
#pragma unroll
            for (int hh = 0; hh < 4; hh++) {
                e0[hh] = er_in[j0 * 8 + h0 + hh];
                e1[hh] = er_in[j1 * 8 + h0 + hh];
            }
#pragma unroll
            for (int hh = 0; hh < 4; hh++) {
                float s0 = eli[hh] + e0[hh];
                float s1 = eli[hh] + e1[hh];
                s0 = s0 > 0.f ? s0 : 0.2f * s0;
                s1 = s1 > 0.f ? s1 : 0.2f * s1;
                float w0 = __expf(s0), w1 = __expf(s1);
                acc[hh] = fmaf(w0, xv0, acc[hh]);
                acc[hh] = fmaf(w1, xv1, acc[hh]);
                den[hh] += w0 + w1;
            }
        }
        if (k < dg) {
            int j = nb[k];
            float xv = x_in[(size_t)j * DH + lane];
#pragma unroll
            for (int hh = 0; hh < 4; hh++) {
                float s = eli[hh] + er_in[j * 8 + h0 + hh];
                s = s > 0.f ? s : 0.2f * s;
                float w = __expf(s);
                acc[hh] = fmaf(w, xv, acc[hh]);
                den[hh] += w;
            }
        }
#pragma unroll
        for (int hh = 0; hh < 4; hh++) {
            float o = acc[hh] / fmaxf(den[hh], 1e-12f) + bv;
            o = o > 0.f ? o : __expf(o) - 1.f;    // elu
            h_s[t >> 1][(h0 + hh) * DH + lane] = o;
        }
    }
    __syncthreads();

    // ---- Phase B: mm + proj from LDS
    const int g = wv >> 2;                // node-group (4 nodes)
    const int kq = wv & 3;                // K-quarter
    float acc[4] = {0.f, 0.f, 0.f, 0.f};
    const int k0 = kq * (FDIM / 4);
    for (int k = k0; k < k0 + FDIM / 4; k += 4) {
        float w0 = W[(k + 0) * DH + lane];
        float w1 = W[(k + 1) * DH + lane];
        float w2 = W[(k + 2) * DH + lane];
        float w3 = W[(k + 3) * DH + lane];
#pragma unroll
        for (int r = 0; r < 4; r++) {
            float4 a = *reinterpret_cast<const float4*>(&h_s[g * 4 + r][k]);
            acc[r] = fmaf(a.x, w0, fmaf(a.y, w1, fmaf(a.z, w2, fmaf(a.w, w3, acc[r]))));
        }
    }
#pragma unroll
    for (int r = 0; r < 4; r++) part[g][kq][r][lane] = acc[r];
    __syncthreads();

    float xv = part[g][0][kq][lane] + part[g][1][kq][lane]
             + part[g][2][kq][lane] + part[g][3][kq][lane];
    const int node = n0 + g * 4 + kq;
    x_out[(size_t)node * DH + lane] = xv;
#pragma unroll
    for (int hh = 0; hh < PROJ_H; hh++) {
        float vl = xv * al[lane * PROJ_H + hh];
        float vr = xv * ar[lane * PROJ_H + hh];
#pragma unroll
        for (int off = 32; off >= 1; off >>= 1) {
            vl += __shfl_xor(vl, off, 64);
            vr += __shfl_xor(vr, off, 64);
        }
        if (lane == 0) {
            el_out[node * PROJ_H + hh] = vl;
            er_out[node * PROJ_H + hh] = vr;
        }
    }
}

// ---------------------------------------------------------------------------
// Kernel 4: final aggregate (H=1, no activation) -> d_out.
// ---------------------------------------------------------------------------
__global__ __launch_bounds__(256) void k_agg_final(
    const float* __restrict__ x_in, const float* __restrict__ el_in,
    const float* __restrict__ er_in, const int* __restrict__ nbr,
    const int* __restrict__ deg, const float* __restrict__ bias,
    float* __restrict__ out)
{
    const int node = blockIdx.x * 4 + (threadIdx.x >> 6);
    const int lane = threadIdx.x & 63;
    const float eli = el_in[node];
    float acc = 0.f, den = 0.f;
    const int dg = deg[node];
    const int* nb = nbr + (size_t)node * CAP;
    int k = 0;
    for (; k + 2 <= dg; k += 2) {
        int j0 = nb[k], j1 = nb[k + 1];
        float xv0 = x_in[(size_t)j0 * DH + lane];
        float xv1 = x_in[(size_t)j1 * DH + lane];
        float s0 = eli + er_in[j0];
        float s1 = eli + er_in[j1];
        s0 = s0 > 0.f ? s0 : 0.2f * s0;
        s1 = s1 > 0.f ? s1 : 0.2f * s1;
        float w0 = __expf(s0), w1 = __expf(s1);
        acc = fmaf(w0, xv0, acc);
        acc = fmaf(w1, xv1, acc);
        den += w0 + w1;
    }
    if (k < dg) {
        int j = nb[k];
        float s = eli + er_in[j];
        s = s > 0.f ? s : 0.2f * s;
        float w = __expf(s);
        acc = fmaf(w, x_in[(size_t)j * DH + lane], acc);
        den += w;
    }
    out[(size_t)node * DH + lane] = acc / fmaxf(den, 1e-12f) + bias[lane];
}

// ---------------------------------------------------------------------------
extern "C" void kernel_launch(void* const* d_in, const int* in_sizes, int n_in,
                              void* d_out, int out_size, void* d_ws, size_t ws_size,
                              hipStream_t stream)
{
    const float* adj  = (const float*)d_in[0];
    const float* feat = (const float*)d_in[1];
    const float* W0   = (const float*)d_in[2];
    const float* al0  = (const float*)d_in[3];
    const float* ar0  = (const float*)d_in[4];
    const float* b0   = (const float*)d_in[5];
    const float* W1   = (const float*)d_in[6];
    const float* al1  = (const float*)d_in[7];
    const float* ar1  = (const float*)d_in[8];
    const float* b1   = (const float*)d_in[9];
    const float* W2   = (const float*)d_in[10];
    const float* al2  = (const float*)d_in[11];
    const float* ar2  = (const float*)d_in[12];
    const float* b2   = (const float*)d_in[13];
    float* out = (float*)d_out;

    // workspace: double-buffered x/el/er (ping-pong across fused layers)
    char* ws = (char*)d_ws;
    int*   nbr = (int*)ws;   ws += (size_t)NNODES * CAP * sizeof(int);   // 2 MB
    int*   deg = (int*)ws;   ws += (size_t)NNODES * sizeof(int);         // 16 KB
    float* x0  = (float*)ws; ws += (size_t)NNODES * DH * sizeof(float);  // 1 MB
    float* x1  = (float*)ws; ws += (size_t)NNODES * DH * sizeof(float);  // 1 MB
    float* elA = (float*)ws; ws += (size_t)NNODES * 8 * sizeof(float);   // 128 KB
    float* erA = (float*)ws; ws += (size_t)NNODES * 8 * sizeof(float);   // 128 KB
    float* elB = (float*)ws; ws += (size_t)NNODES * 8 * sizeof(float);   // 128 KB
    float* erB = (float*)ws; ws += (size_t)NNODES * 8 * sizeof(float);   // 128 KB

    // K1: build (4096 blocks) + layer-0 mm/proj (1024 blocks)
    k_build_mm0<<<NNODES + NNODES / 4, 256, 0, stream>>>(
        adj, nbr, deg, feat, W0, al0, ar0, x0, elA, erA);

    // K2: agg0 + mm1/proj1   (x0,elA,erA -> x1,elB,erB)
    k_agg_mm<8><<<NNODES / 8, 512, 0, stream>>>(
        x0, elA, erA, nbr, deg, b0, W1, al1, ar1, x1, elB, erB);

    // K3: agg1 + mm2/proj2   (x1,elB,erB -> x0,elA,erA; PROJ_H=1)
    k_agg_mm<1><<<NNODES / 8, 512, 0, stream>>>(
        x1, elB, erB, nbr, deg, b1, W2, al2, ar2, x0, elA, erA);

    // K4: final aggregate (H=1, no act) -> out
    k_agg_final<<<NNODES / 4, 256, 0, stream>>>(x0, elA, erA, nbr, deg, b2, out);
}

// Round 5
// 231.237 us; speedup vs baseline: 4.5875x; 1.0171x over previous
//
#include <hip/hip_runtime.h>
#include <cmath>

#define NNODES 4096
#define FDIM 512
#define DH 64
#define CAP 128

// ---------------------------------------------------------------------------
// Kernel 1 (heterogeneous): blocks [0,1024) run layer-0 mm+proj (long serial
// K-chains — dispatched FIRST so they hide under the build scan); blocks
// [1024, 1024+4096) build neighbor lists (one block per adjacency row).
// Build issues all 4 float4 row-loads straight-line before any processing:
// 4 KB in flight per wave -> BW-bound (was 1 load in flight -> 800 GB/s).
// ---------------------------------------------------------------------------
__global__ __launch_bounds__(256) void k_mm0_build(
    const float* __restrict__ adj, int* __restrict__ nbr, int* __restrict__ deg,
    const float* __restrict__ feat, const float* __restrict__ W0,
    const float* __restrict__ al0, const float* __restrict__ ar0,
    float* __restrict__ x, float* __restrict__ el, float* __restrict__ er)
{
    __shared__ float part[4][4][DH];   // mm role: 4 KB
    __shared__ int cnt;                // build role

    if (blockIdx.x >= NNODES / 4) {
        // ---- build role
        const int row = blockIdx.x - NNODES / 4;
        if (threadIdx.x == 0) cnt = 0;
        __syncthreads();
        const float4* arow = reinterpret_cast<const float4*>(adj + (size_t)row * NNODES);
        int* nrow = nbr + (size_t)row * CAP;
        float4 v0 = arow[threadIdx.x];
        float4 v1 = arow[threadIdx.x + 256];
        float4 v2 = arow[threadIdx.x + 512];
        float4 v3 = arow[threadIdx.x + 768];
        int b0 = threadIdx.x * 4, b1 = (threadIdx.x + 256) * 4,
            b2 = (threadIdx.x + 512) * 4, b3 = (threadIdx.x + 768) * 4;
        if (v0.x != 0.f) { int p = atomicAdd(&cnt, 1); if (p < CAP) nrow[p] = b0 + 0; }
        if (v0.y != 0.f) { int p = atomicAdd(&cnt, 1); if (p < CAP) nrow[p] = b0 + 1; }
        if (v0.z != 0.f) { int p = atomicAdd(&cnt, 1); if (p < CAP) nrow[p] = b0 + 2; }
        if (v0.w != 0.f) { int p = atomicAdd(&cnt, 1); if (p < CAP) nrow[p] = b0 + 3; }
        if (v1.x != 0.f) { int p = atomicAdd(&cnt, 1); if (p < CAP) nrow[p] = b1 + 0; }
        if (v1.y != 0.f) { int p = atomicAdd(&cnt, 1); if (p < CAP) nrow[p] = b1 + 1; }
        if (v1.z != 0.f) { int p = atomicAdd(&cnt, 1); if (p < CAP) nrow[p] = b1 + 2; }
        if (v1.w != 0.f) { int p = atomicAdd(&cnt, 1); if (p < CAP) nrow[p] = b1 + 3; }
        if (v2.x != 0.f) { int p = atomicAdd(&cnt, 1); if (p < CAP) nrow[p] = b2 + 0; }
        if (v2.y != 0.f) { int p = atomicAdd(&cnt, 1); if (p < CAP) nrow[p] = b2 + 1; }
        if (v2.z != 0.f) { int p = atomicAdd(&cnt, 1); if (p < CAP) nrow[p] = b2 + 2; }
        if (v2.w != 0.f) { int p = atomicAdd(&cnt, 1); if (p < CAP) nrow[p] = b2 + 3; }
        if (v3.x != 0.f) { int p = atomicAdd(&cnt, 1); if (p < CAP) nrow[p] = b3 + 0; }
        if (v3.y != 0.f) { int p = atomicAdd(&cnt, 1); if (p < CAP) nrow[p] = b3 + 1; }
        if (v3.z != 0.f) { int p = atomicAdd(&cnt, 1); if (p < CAP) nrow[p] = b3 + 2; }
        if (v3.w != 0.f) { int p = atomicAdd(&cnt, 1); if (p < CAP) nrow[p] = b3 + 3; }
        __syncthreads();
        if (threadIdx.x == 0) deg[row] = cnt < CAP ? cnt : CAP;
        return;
    }

    // ---- mm0+proj0 role: 4 nodes per block, wave = K-quarter, k+=8 unroll
    const int lane = threadIdx.x & 63;
    const int kq = threadIdx.x >> 6;
    const int r0 = blockIdx.x * 4;

    float acc[4] = {0.f, 0.f, 0.f, 0.f};
    const int k0 = kq * (FDIM / 4);
    for (int k = k0; k < k0 + FDIM / 4; k += 8) {
        float w[8];
#pragma unroll
        for (int u = 0; u < 8; u++) w[u] = W0[(k + u) * DH + lane];
        float4 a[4][2];
#pragma unroll
        for (int r = 0; r < 4; r++) {
            a[r][0] = *reinterpret_cast<const float4*>(feat + (size_t)(r0 + r) * FDIM + k);
            a[r][1] = *reinterpret_cast<const float4*>(feat + (size_t)(r0 + r) * FDIM + k + 4);
        }
#pragma unroll
        for (int r = 0; r < 4; r++) {
            acc[r] = fmaf(a[r][0].x, w[0], fmaf(a[r][0].y, w[1], fmaf(a[r][0].z, w[2], fmaf(a[r][0].w, w[3], acc[r]))));
            acc[r] = fmaf(a[r][1].x, w[4], fmaf(a[r][1].y, w[5], fmaf(a[r][1].z, w[6], fmaf(a[r][1].w, w[7], acc[r]))));
        }
    }
#pragma unroll
    for (int r = 0; r < 4; r++) part[kq][r][lane] = acc[r];
    __syncthreads();

    float xv = part[0][kq][lane] + part[1][kq][lane] + part[2][kq][lane] + part[3][kq][lane];
    const int node = r0 + kq;
    x[(size_t)node * DH + lane] = xv;
#pragma unroll
    for (int hh = 0; hh < 8; hh++) {
        float vl = xv * al0[lane * 8 + hh];
        float vr = xv * ar0[lane * 8 + hh];
#pragma unroll
        for (int off = 32; off >= 1; off >>= 1) {
            vl += __shfl_xor(vl, off, 64);
            vr += __shfl_xor(vr, off, 64);
        }
        if (lane == 0) {
            el[node * 8 + hh] = vl;
            er[node * 8 + hh] = vr;
        }
    }
}

// ---------------------------------------------------------------------------
// Kernel 2/3 (fused agg_L + mm_{L+1} + proj): block owns 8 nodes.
// Phase A: 8-head aggregate -> LDS h_s[8][512] (el/er loaded as float4).
// Phase B: x_out = h_s @ W from LDS, then el/er shuffle projections.
// x/el/er double-buffered across launches.
// ---------------------------------------------------------------------------
template <int PROJ_H>
__global__ __launch_bounds__(512) void k_agg_mm(
    const float* __restrict__ x_in, const float* __restrict__ el_in,
    const float* __restrict__ er_in, const int* __restrict__ nbr,
    const int* __restrict__ deg, const float* __restrict__ bias_agg,
    const float* __restrict__ W, const float* __restrict__ al,
    const float* __restrict__ ar, float* __restrict__ x_out,
    float* __restrict__ el_out, float* __restrict__ er_out)
{
    __shared__ float h_s[8][FDIM];        // 16 KB
    __shared__ float part[2][4][4][DH];   // 8 KB
    const int lane = threadIdx.x & 63;
    const int wv = threadIdx.x >> 6;      // 0..7
    const int n0 = blockIdx.x * 8;
    const float bv = bias_agg[lane];

    // ---- Phase A: aggregate (2 tasks/wave: node x head-half)
    for (int t = wv; t < 16; t += 8) {
        const int node = n0 + (t >> 1);
        const int h0 = (t & 1) * 4;
        float4 eli = *reinterpret_cast<const float4*>(el_in + node * 8 + h0);
        float acc[4] = {0.f, 0.f, 0.f, 0.f};
        float den[4] = {0.f, 0.f, 0.f, 0.f};
        const int dg = deg[node];
        const int* nb = nbr + (size_t)node * CAP;
        int k = 0;
        for (; k + 2 <= dg; k += 2) {
            int j0 = nb[k], j1 = nb[k + 1];
            float xv0 = x_in[(size_t)j0 * DH + lane];
            float xv1 = x_in[(size_t)j1 * DH + lane];
            float4 e0 = *reinterpret_cast<const float4*>(er_in + j0 * 8 + h0);
            float4 e1 = *reinterpret_cast<const float4*>(er_in + j1 * 8 + h0);
            float s;
            s = eli.x + e0.x; s = s > 0.f ? s : 0.2f * s; float w0x = __expf(s);
            s = eli.y + e0.y; s = s > 0.f ? s : 0.2f * s; float w0y = __expf(s);
            s = eli.z + e0.z; s = s > 0.f ? s : 0.2f * s; float w0z = __expf(s);
            s = eli.w + e0.w; s = s > 0.f ? s : 0.2f * s; float w0w = __expf(s);
            s = eli.x + e1.x; s = s > 0.f ? s : 0.2f * s; float w1x = __expf(s);
            s = eli.y + e1.y; s = s > 0.f ? s : 0.2f * s; float w1y = __expf(s);
            s = eli.z + e1.z; s = s > 0.f ? s : 0.2f * s; float w1z = __expf(s);
            s = eli.w + e1.w; s = s > 0.f ? s : 0.2f * s; float w1w = __expf(s);
            acc[0] = fmaf(w0x, xv0, fmaf(w1x, xv1, acc[0])); den[0] += w0x + w1x;
            acc[1] = fmaf(w0y, xv0, fmaf(w1y, xv1, acc[1])); den[1] += w0y + w1y;
            acc[2] = fmaf(w0z, xv0, fmaf(w1z, xv1, acc[2])); den[2] += w0z + w1z;
            acc[3] = fmaf(w0w, xv0, fmaf(w1w, xv1, acc[3])); den[3] += w0w + w1w;
        }
        if (k < dg) {
            int j = nb[k];
            float xv = x_in[(size_t)j * DH + lane];
            float4 e0 = *reinterpret_cast<const float4*>(er_in + j * 8 + h0);
            float s;
            s = eli.x + e0.x; s = s > 0.f ? s : 0.2f * s; float w0 = __expf(s);
            s = eli.y + e0.y; s = s > 0.f ? s : 0.2f * s; float w1 = __expf(s);
            s = eli.z + e0.z; s = s > 0.f ? s : 0.2f * s; float w2 = __expf(s);
            s = eli.w + e0.w; s = s > 0.f ? s : 0.2f * s; float w3 = __expf(s);
            acc[0] = fmaf(w0, xv, acc[0]); den[0] += w0;
            acc[1] = fmaf(w1, xv, acc[1]); den[1] += w1;
            acc[2] = fmaf(w2, xv, acc[2]); den[2] += w2;
            acc[3] = fmaf(w3, xv, acc[3]); den[3] += w3;
        }
#pragma unroll
        for (int hh = 0; hh < 4; hh++) {
            float o = acc[hh] / fmaxf(den[hh], 1e-12f) + bv;
            o = o > 0.f ? o : __expf(o) - 1.f;    // elu
            h_s[t >> 1][(h0 + hh) * DH + lane] = o;
        }
    }
    __syncthreads();

    // ---- Phase B: mm + proj from LDS (k+=8 unroll)
    const int g = wv >> 2;
    const int kq = wv & 3;
    float acc[4] = {0.f, 0.f, 0.f, 0.f};
    const int k0 = kq * (FDIM / 4);
    for (int k = k0; k < k0 + FDIM / 4; k += 8) {
        float w[8];
#pragma unroll
        for (int u = 0; u < 8; u++) w[u] = W[(k + u) * DH + lane];
#pragma unroll
        for (int r = 0; r < 4; r++) {
            float4 a0 = *reinterpret_cast<const float4*>(&h_s[g * 4 + r][k]);
            float4 a1 = *reinterpret_cast<const float4*>(&h_s[g * 4 + r][k + 4]);
            acc[r] = fmaf(a0.x, w[0], fmaf(a0.y, w[1], fmaf(a0.z, w[2], fmaf(a0.w, w[3], acc[r]))));
            acc[r] = fmaf(a1.x, w[4], fmaf(a1.y, w[5], fmaf(a1.z, w[6], fmaf(a1.w, w[7], acc[r]))));
        }
    }
#pragma unroll
    for (int r = 0; r < 4; r++) part[g][kq][r][lane] = acc[r];
    __syncthreads();

    float xv = part[g][0][kq][lane] + part[g][1][kq][lane]
             + part[g][2][kq][lane] + part[g][3][kq][lane];
    const int node = n0 + g * 4 + kq;
    x_out[(size_t)node * DH + lane] = xv;
#pragma unroll
    for (int hh = 0; hh < PROJ_H; hh++) {
        float vl = xv * al[lane * PROJ_H + hh];
        float vr = xv * ar[lane * PROJ_H + hh];
#pragma unroll
        for (int off = 32; off >= 1; off >>= 1) {
            vl += __shfl_xor(vl, off, 64);
            vr += __shfl_xor(vr, off, 64);
        }
        if (lane == 0) {
            el_out[node * PROJ_H + hh] = vl;
            er_out[node * PROJ_H + hh] = vr;
        }
    }
}

// ---------------------------------------------------------------------------
// Kernel 4: final aggregate (H=1, no activation) -> d_out.
// ---------------------------------------------------------------------------
__global__ __launch_bounds__(256) void k_agg_final(
    const float* __restrict__ x_in, const float* __restrict__ el_in,
    const float* __restrict__ er_in, const int* __restrict__ nbr,
    const int* __restrict__ deg, const float* __restrict__ bias,
    float* __restrict__ out)
{
    const int node = blockIdx.x * 4 + (threadIdx.x >> 6);
    const int lane = threadIdx.x & 63;
    const float eli = el_in[node];
    float acc = 0.f, den = 0.f;
    const int dg = deg[node];
    const int* nb = nbr + (size_t)node * CAP;
    int k = 0;
    for (; k + 2 <= dg; k += 2) {
        int j0 = nb[k], j1 = nb[k + 1];
        float xv0 = x_in[(size_t)j0 * DH + lane];
        float xv1 = x_in[(size_t)j1 * DH + lane];
        float s0 = eli + er_in[j0];
        float s1 = eli + er_in[j1];
        s0 = s0 > 0.f ? s0 : 0.2f * s0;
        s1 = s1 > 0.f ? s1 : 0.2f * s1;
        float w0 = __expf(s0), w1 = __expf(s1);
        acc = fmaf(w0, xv0, acc);
        acc = fmaf(w1, xv1, acc);
        den += w0 + w1;
    }
    if (k < dg) {
        int j = nb[k];
        float s = eli + er_in[j];
        s = s > 0.f ? s : 0.2f * s;
        float w = __expf(s);
        acc = fmaf(w, x_in[(size_t)j * DH + lane], acc);
        den += w;
    }
    out[(size_t)node * DH + lane] = acc / fmaxf(den, 1e-12f) + bias[lane];
}

// ---------------------------------------------------------------------------
extern "C" void kernel_launch(void* const* d_in, const int* in_sizes, int n_in,
                              void* d_out, int out_size, void* d_ws, size_t ws_size,
                              hipStream_t stream)
{
    const float* adj  = (const float*)d_in[0];
    const float* feat = (const float*)d_in[1];
    const float* W0   = (const float*)d_in[2];
    const float* al0  = (const float*)d_in[3];
    const float* ar0  = (const float*)d_in[4];
    const float* b0   = (const float*)d_in[5];
    const float* W1   = (const float*)d_in[6];
    const float* al1  = (const float*)d_in[7];
    const float* ar1  = (const float*)d_in[8];
    const float* b1   = (const float*)d_in[9];
    const float* W2   = (const float*)d_in[10];
    const float* al2  = (const float*)d_in[11];
    const float* ar2  = (const float*)d_in[12];
    const float* b2   = (const float*)d_in[13];
    float* out = (float*)d_out;

    char* ws = (char*)d_ws;
    int*   nbr = (int*)ws;   ws += (size_t)NNODES * CAP * sizeof(int);   // 2 MB
    int*   deg = (int*)ws;   ws += (size_t)NNODES * sizeof(int);         // 16 KB
    float* x0  = (float*)ws; ws += (size_t)NNODES * DH * sizeof(float);  // 1 MB
    float* x1  = (float*)ws; ws += (size_t)NNODES * DH * sizeof(float);  // 1 MB
    float* elA = (float*)ws; ws += (size_t)NNODES * 8 * sizeof(float);   // 128 KB
    float* erA = (float*)ws; ws += (size_t)NNODES * 8 * sizeof(float);   // 128 KB
    float* elB = (float*)ws; ws += (size_t)NNODES * 8 * sizeof(float);   // 128 KB
    float* erB = (float*)ws; ws += (size_t)NNODES * 8 * sizeof(float);   // 128 KB

    // K1: layer-0 mm/proj (blocks 0..1023, launched first) + build (4096 blocks)
    k_mm0_build<<<NNODES / 4 + NNODES, 256, 0, stream>>>(
        adj, nbr, deg, feat, W0, al0, ar0, x0, elA, erA);

    // K2: agg0 + mm1/proj1   (x0,elA,erA -> x1,elB,erB)
    k_agg_mm<8><<<NNODES / 8, 512, 0, stream>>>(
        x0, elA, erA, nbr, deg, b0, W1, al1, ar1, x1, elB, erB);

    // K3: agg1 + mm2/proj2   (x1,elB,erB -> x0,elA,erA; PROJ_H=1)
    k_agg_mm<1><<<NNODES / 8, 512, 0, stream>>>(
        x1, elB, erB, nbr, deg, b1, W2, al2, ar2, x0, elA, erA);

    // K4: final aggregate (H=1, no act) -> out
    k_agg_final<<<NNODES / 4, 256, 0, stream>>>(x0, elA, erA, nbr, deg, b2, out);
}

// Round 6
// 197.604 us; speedup vs baseline: 5.3683x; 1.1702x over previous
//
#include <hip/hip_runtime.h>
#include <cmath>

#define NNODES 4096
#define FDIM 512
#define DH 64
#define CAP 128

// ---------------------------------------------------------------------------
// Kernel 1 (heterogeneous): blocks [0,1024) run layer-0 mm+proj (long serial
// K-chains, dispatched first to hide under the build scan); blocks
// [1024,1024+4096) build neighbor lists (one block per adjacency row, all 4
// float4 row-loads issued straight-line -> BW-bound).
// ---------------------------------------------------------------------------
__global__ __launch_bounds__(256) void k_mm0_build(
    const float* __restrict__ adj, int* __restrict__ nbr, int* __restrict__ deg,
    const float* __restrict__ feat, const float* __restrict__ W0,
    const float* __restrict__ al0, const float* __restrict__ ar0,
    float* __restrict__ x, float* __restrict__ el, float* __restrict__ er)
{
    __shared__ float part[4][4][DH];
    __shared__ int cnt;

    if (blockIdx.x >= NNODES / 4) {
        const int row = blockIdx.x - NNODES / 4;
        if (threadIdx.x == 0) cnt = 0;
        __syncthreads();
        const float4* arow = reinterpret_cast<const float4*>(adj + (size_t)row * NNODES);
        int* nrow = nbr + (size_t)row * CAP;
        float4 v0 = arow[threadIdx.x];
        float4 v1 = arow[threadIdx.x + 256];
        float4 v2 = arow[threadIdx.x + 512];
        float4 v3 = arow[threadIdx.x + 768];
        int b0 = threadIdx.x * 4, b1 = (threadIdx.x + 256) * 4,
            b2 = (threadIdx.x + 512) * 4, b3 = (threadIdx.x + 768) * 4;
        if (v0.x != 0.f) { int p = atomicAdd(&cnt, 1); if (p < CAP) nrow[p] = b0 + 0; }
        if (v0.y != 0.f) { int p = atomicAdd(&cnt, 1); if (p < CAP) nrow[p] = b0 + 1; }
        if (v0.z != 0.f) { int p = atomicAdd(&cnt, 1); if (p < CAP) nrow[p] = b0 + 2; }
        if (v0.w != 0.f) { int p = atomicAdd(&cnt, 1); if (p < CAP) nrow[p] = b0 + 3; }
        if (v1.x != 0.f) { int p = atomicAdd(&cnt, 1); if (p < CAP) nrow[p] = b1 + 0; }
        if (v1.y != 0.f) { int p = atomicAdd(&cnt, 1); if (p < CAP) nrow[p] = b1 + 1; }
        if (v1.z != 0.f) { int p = atomicAdd(&cnt, 1); if (p < CAP) nrow[p] = b1 + 2; }
        if (v1.w != 0.f) { int p = atomicAdd(&cnt, 1); if (p < CAP) nrow[p] = b1 + 3; }
        if (v2.x != 0.f) { int p = atomicAdd(&cnt, 1); if (p < CAP) nrow[p] = b2 + 0; }
        if (v2.y != 0.f) { int p = atomicAdd(&cnt, 1); if (p < CAP) nrow[p] = b2 + 1; }
        if (v2.z != 0.f) { int p = atomicAdd(&cnt, 1); if (p < CAP) nrow[p] = b2 + 2; }
        if (v2.w != 0.f) { int p = atomicAdd(&cnt, 1); if (p < CAP) nrow[p] = b2 + 3; }
        if (v3.x != 0.f) { int p = atomicAdd(&cnt, 1); if (p < CAP) nrow[p] = b3 + 0; }
        if (v3.y != 0.f) { int p = atomicAdd(&cnt, 1); if (p < CAP) nrow[p] = b3 + 1; }
        if (v3.z != 0.f) { int p = atomicAdd(&cnt, 1); if (p < CAP) nrow[p] = b3 + 2; }
        if (v3.w != 0.f) { int p = atomicAdd(&cnt, 1); if (p < CAP) nrow[p] = b3 + 3; }
        __syncthreads();
        if (threadIdx.x == 0) deg[row] = cnt < CAP ? cnt : CAP;
        return;
    }

    // ---- mm0+proj0: 4 nodes per block, wave = K-quarter
    const int lane = threadIdx.x & 63;
    const int kq = threadIdx.x >> 6;
    const int r0 = blockIdx.x * 4;

    float acc[4] = {0.f, 0.f, 0.f, 0.f};
    const int k0 = kq * (FDIM / 4);
    for (int k = k0; k < k0 + FDIM / 4; k += 8) {
        float w[8];
#pragma unroll
        for (int u = 0; u < 8; u++) w[u] = W0[(k + u) * DH + lane];
#pragma unroll
        for (int r = 0; r < 4; r++) {
            float4 a0 = *reinterpret_cast<const float4*>(feat + (size_t)(r0 + r) * FDIM + k);
            float4 a1 = *reinterpret_cast<const float4*>(feat + (size_t)(r0 + r) * FDIM + k + 4);
            acc[r] = fmaf(a0.x, w[0], fmaf(a0.y, w[1], fmaf(a0.z, w[2], fmaf(a0.w, w[3], acc[r]))));
            acc[r] = fmaf(a1.x, w[4], fmaf(a1.y, w[5], fmaf(a1.z, w[6], fmaf(a1.w, w[7], acc[r]))));
        }
    }
#pragma unroll
    for (int r = 0; r < 4; r++) part[kq][r][lane] = acc[r];
    __syncthreads();

    float xv = part[0][kq][lane] + part[1][kq][lane] + part[2][kq][lane] + part[3][kq][lane];
    const int node = r0 + kq;
    x[(size_t)node * DH + lane] = xv;
#pragma unroll
    for (int hh = 0; hh < 8; hh++) {
        float vl = xv * al0[lane * 8 + hh];
        float vr = xv * ar0[lane * 8 + hh];
#pragma unroll
        for (int off = 32; off >= 1; off >>= 1) {
            vl += __shfl_xor(vl, off, 64);
            vr += __shfl_xor(vr, off, 64);
        }
        if (lane == 0) {
            el[node * 8 + hh] = vl;
            er[node * 8 + hh] = vr;
        }
    }
}

// ---------------------------------------------------------------------------
// Kernel 2/3 (fused agg_L + mm_{L+1} + proj): block = 4 nodes, 256 threads.
// Phase A per wave-task (node, head-half), two-round pipeline per 16 nbrs:
//   weight round: 64 lanes = 16 nbrs x 4 heads, ONE expf per (j,h) (no
//     64-way lane redundancy), weights -> 1KB LDS tile, den accumulated
//     per-lane and tree-reduced once per task.
//   aggregate round: 16 unrolled iters {shfl j, broadcast ds_read_b128 w4,
//     coalesced x load, 4 fma}. Padded lanes carry w=0 (branch-free).
// Phase B: x_out = h_s @ W from LDS (wave = K-quarter), then el/er proj.
// ---------------------------------------------------------------------------
template <int PROJ_H>
__global__ __launch_bounds__(256) void k_agg_mm(
    const float* __restrict__ x_in, const float* __restrict__ el_in,
    const float* __restrict__ er_in, const int* __restrict__ nbr,
    const int* __restrict__ deg, const float* __restrict__ bias_agg,
    const float* __restrict__ W, const float* __restrict__ al,
    const float* __restrict__ ar, float* __restrict__ x_out,
    float* __restrict__ el_out, float* __restrict__ er_out)
{
    __shared__ float h_s[4][FDIM];     // 8 KB
    __shared__ float part[4][4][DH];   // 4 KB
    __shared__ float w_s[4][16][4];    // 1 KB
    const int lane = threadIdx.x & 63;
    const int wv = threadIdx.x >> 6;   // 0..3
    const int n0 = blockIdx.x * 4;
    const float bv = bias_agg[lane];

    // ---- Phase A: 8 tasks (node x head-half) over 4 waves
    for (int t = wv; t < 8; t += 4) {
        const int node = n0 + (t >> 1);
        const int h0 = (t & 1) * 4;
        const float eli = el_in[node * 8 + h0 + (lane & 3)];
        float acc[4] = {0.f, 0.f, 0.f, 0.f};
        float denp = 0.f;
        const int dg = deg[node];
        const int* nb = nbr + (size_t)node * CAP;

        for (int c0 = 0; c0 < dg; c0 += 16) {
            // weight round: lane = (local nbr, head)
            int jj = c0 + (lane >> 2);
            int jidx = jj < dg ? jj : dg - 1;
            int j = nb[jidx];
            float e = er_in[j * 8 + h0 + (lane & 3)];
            float s = eli + e;
            s = s > 0.f ? s : 0.2f * s;
            float w = (jj < dg) ? __expf(s) : 0.f;
            w_s[wv][lane >> 2][lane & 3] = w;
            denp += w;
            // aggregate round: lane = feature dim
#pragma unroll
            for (int k = 0; k < 16; k++) {
                int jk = __shfl(j, 4 * k, 64);
                float4 w4 = *reinterpret_cast<const float4*>(&w_s[wv][k][0]);
                float xv = x_in[(size_t)jk * DH + lane];
                acc[0] = fmaf(w4.x, xv, acc[0]);
                acc[1] = fmaf(w4.y, xv, acc[1]);
                acc[2] = fmaf(w4.z, xv, acc[2]);
                acc[3] = fmaf(w4.w, xv, acc[3]);
            }
        }
        // reduce den over the 16 lanes sharing each (lane&3)
        denp += __shfl_xor(denp, 4, 64);
        denp += __shfl_xor(denp, 8, 64);
        denp += __shfl_xor(denp, 16, 64);
        denp += __shfl_xor(denp, 32, 64);
#pragma unroll
        for (int hh = 0; hh < 4; hh++) {
            float den = __shfl(denp, hh, 64);      // lane hh holds den[hh]
            float o = acc[hh] / fmaxf(den, 1e-12f) + bv;
            o = o > 0.f ? o : __expf(o) - 1.f;     // elu
            h_s[t >> 1][(h0 + hh) * DH + lane] = o;
        }
    }
    __syncthreads();

    // ---- Phase B: mm + proj from LDS (wave = K-quarter)
    float acc[4] = {0.f, 0.f, 0.f, 0.f};
    const int k0 = wv * (FDIM / 4);
    for (int k = k0; k < k0 + FDIM / 4; k += 8) {
        float w[8];
#pragma unroll
        for (int u = 0; u < 8; u++) w[u] = W[(k + u) * DH + lane];
#pragma unroll
        for (int r = 0; r < 4; r++) {
            float4 a0 = *reinterpret_cast<const float4*>(&h_s[r][k]);
            float4 a1 = *reinterpret_cast<const float4*>(&h_s[r][k + 4]);
            acc[r] = fmaf(a0.x, w[0], fmaf(a0.y, w[1], fmaf(a0.z, w[2], fmaf(a0.w, w[3], acc[r]))));
            acc[r] = fmaf(a1.x, w[4], fmaf(a1.y, w[5], fmaf(a1.z, w[6], fmaf(a1.w, w[7], acc[r]))));
        }
    }
#pragma unroll
    for (int r = 0; r < 4; r++) part[wv][r][lane] = acc[r];
    __syncthreads();

    float xv = part[0][wv][lane] + part[1][wv][lane]
             + part[2][wv][lane] + part[3][wv][lane];
    const int node = n0 + wv;
    x_out[(size_t)node * DH + lane] = xv;
#pragma unroll
    for (int hh = 0; hh < PROJ_H; hh++) {
        float vl = xv * al[lane * PROJ_H + hh];
        float vr = xv * ar[lane * PROJ_H + hh];
#pragma unroll
        for (int off = 32; off >= 1; off >>= 1) {
            vl += __shfl_xor(vl, off, 64);
            vr += __shfl_xor(vr, off, 64);
        }
        if (lane == 0) {
            el_out[node * PROJ_H + hh] = vl;
            er_out[node * PROJ_H + hh] = vr;
        }
    }
}

// ---------------------------------------------------------------------------
// Kernel 4: final aggregate (H=1, no activation) -> d_out. Wave per node;
// weight round uses 64 lanes = 64 neighbors (one expf each), then a
// runtime-bounded aggregate loop with shfl-broadcast weights.
// ---------------------------------------------------------------------------
__global__ __launch_bounds__(256) void k_agg_final(
    const float* __restrict__ x_in, const float* __restrict__ el_in,
    const float* __restrict__ er_in, const int* __restrict__ nbr,
    const int* __restrict__ deg, const float* __restrict__ bias,
    float* __restrict__ out)
{
    const int node = blockIdx.x * 4 + (threadIdx.x >> 6);
    const int lane = threadIdx.x & 63;
    const float eli = el_in[node];
    float acc = 0.f, denp = 0.f;
    const int dg = deg[node];
    const int* nb = nbr + (size_t)node * CAP;

    for (int c0 = 0; c0 < dg; c0 += 64) {
        int jj = c0 + lane;
        int jidx = jj < dg ? jj : dg - 1;
        int j = nb[jidx];
        float e = er_in[j];
        float s = eli + e;
        s = s > 0.f ? s : 0.2f * s;
        float w = (jj < dg) ? __expf(s) : 0.f;
        denp += w;
        int cnt = dg - c0; cnt = cnt < 64 ? cnt : 64;
#pragma unroll 4
        for (int k = 0; k < cnt; k++) {
            int jk = __shfl(j, k, 64);
            float wk = __shfl(w, k, 64);
            float xv = x_in[(size_t)jk * DH + lane];
            acc = fmaf(wk, xv, acc);
        }
    }
#pragma unroll
    for (int off = 32; off >= 1; off >>= 1) denp += __shfl_xor(denp, off, 64);
    out[(size_t)node * DH + lane] = acc / fmaxf(denp, 1e-12f) + bias[lane];
}

// ---------------------------------------------------------------------------
extern "C" void kernel_launch(void* const* d_in, const int* in_sizes, int n_in,
                              void* d_out, int out_size, void* d_ws, size_t ws_size,
                              hipStream_t stream)
{
    const float* adj  = (const float*)d_in[0];
    const float* feat = (const float*)d_in[1];
    const float* W0   = (const float*)d_in[2];
    const float* al0  = (const float*)d_in[3];
    const float* ar0  = (const float*)d_in[4];
    const float* b0   = (const float*)d_in[5];
    const float* W1   = (const float*)d_in[6];
    const float* al1  = (const float*)d_in[7];
    const float* ar1  = (const float*)d_in[8];
    const float* b1   = (const float*)d_in[9];
    const float* W2   = (const float*)d_in[10];
    const float* al2  = (const float*)d_in[11];
    const float* ar2  = (const float*)d_in[12];
    const float* b2   = (const float*)d_in[13];
    float* out = (float*)d_out;

    char* ws = (char*)d_ws;
    int*   nbr = (int*)ws;   ws += (size_t)NNODES * CAP * sizeof(int);   // 2 MB
    int*   deg = (int*)ws;   ws += (size_t)NNODES * sizeof(int);         // 16 KB
    float* x0  = (float*)ws; ws += (size_t)NNODES * DH * sizeof(float);  // 1 MB
    float* x1  = (float*)ws; ws += (size_t)NNODES * DH * sizeof(float);  // 1 MB
    float* elA = (float*)ws; ws += (size_t)NNODES * 8 * sizeof(float);   // 128 KB
    float* erA = (float*)ws; ws += (size_t)NNODES * 8 * sizeof(float);   // 128 KB
    float* elB = (float*)ws; ws += (size_t)NNODES * 8 * sizeof(float);   // 128 KB
    float* erB = (float*)ws; ws += (size_t)NNODES * 8 * sizeof(float);   // 128 KB

    // K1: layer-0 mm/proj (blocks 0..1023, first) + build (4096 blocks)
    k_mm0_build<<<NNODES / 4 + NNODES, 256, 0, stream>>>(
        adj, nbr, deg, feat, W0, al0, ar0, x0, elA, erA);

    // K2: agg0 + mm1/proj1   (x0,elA,erA -> x1,elB,erB)
    k_agg_mm<8><<<NNODES / 4, 256, 0, stream>>>(
        x0, elA, erA, nbr, deg, b0, W1, al1, ar1, x1, elB, erB);

    // K3: agg1 + mm2/proj2   (x1,elB,erB -> x0,elA,erA; PROJ_H=1)
    k_agg_mm<1><<<NNODES / 4, 256, 0, stream>>>(
        x1, elB, erB, nbr, deg, b1, W2, al2, ar2, x0, elA, erA);

    // K4: final aggregate (H=1, no act) -> out
    k_agg_final<<<NNODES / 4, 256, 0, stream>>>(x0, elA, erA, nbr, deg, b2, out);
}

// Round 7
// 189.394 us; speedup vs baseline: 5.6010x; 1.0434x over previous
//
#include <hip/hip_runtime.h>
#include <cmath>

#define NNODES 4096
#define FDIM 512
#define DH 64
#define CAP 128

// ---------------------------------------------------------------------------
// Kernel 1 (heterogeneous): blocks [0,1024) run layer-0 mm+proj; blocks
// [1024,1024+4096) build neighbor lists (one block per adjacency row).
// mm role: feat rows staged to LDS via coalesced float4 loads (the old code
//   issued wave-uniform 16B broadcast loads — 1/64th of the pipe).
// build role: ballot-compaction — one LDS atomic per wave per round, and
//   empty rounds (expected ~70%) skipped with a single uniform branch.
// ---------------------------------------------------------------------------
__global__ __launch_bounds__(256) void k_mm0_build(
    const float* __restrict__ adj, int* __restrict__ nbr, int* __restrict__ deg,
    const float* __restrict__ feat, const float* __restrict__ W0,
    const float* __restrict__ al0, const float* __restrict__ ar0,
    float* __restrict__ x, float* __restrict__ el, float* __restrict__ er)
{
    __shared__ float feat_s[4][FDIM];   // 8 KB (mm role)
    __shared__ float part[4][4][DH];    // 4 KB (mm role)
    __shared__ int cnt;                 // build role
    const int lane = threadIdx.x & 63;

    if (blockIdx.x >= NNODES / 4) {
        // ---- build role: one adjacency row, ballot compaction
        const int row = blockIdx.x - NNODES / 4;
        if (threadIdx.x == 0) cnt = 0;
        __syncthreads();
        const float4* arow = reinterpret_cast<const float4*>(adj + (size_t)row * NNODES);
        int* nrow = nbr + (size_t)row * CAP;
        float4 v[4];
        v[0] = arow[threadIdx.x];
        v[1] = arow[threadIdx.x + 256];
        v[2] = arow[threadIdx.x + 512];
        v[3] = arow[threadIdx.x + 768];
        const unsigned long long lmask = (1ull << lane) - 1ull;
#pragma unroll
        for (int s = 0; s < 4; s++) {
            const int colbase = (threadIdx.x + s * 256) * 4;
            float vals[4] = {v[s].x, v[s].y, v[s].z, v[s].w};
#pragma unroll
            for (int e = 0; e < 4; e++) {
                bool nz = vals[e] != 0.f;
                unsigned long long m = __ballot(nz);
                if (m) {                               // wave-uniform skip
                    int base = 0;
                    if (lane == 0) base = atomicAdd(&cnt, __popcll(m));
                    base = __shfl(base, 0, 64);
                    if (nz) {
                        int idx = base + __popcll(m & lmask);
                        if (idx < CAP) nrow[idx] = colbase + e;
                    }
                }
            }
        }
        __syncthreads();
        if (threadIdx.x == 0) deg[row] = cnt < CAP ? cnt : CAP;
        return;
    }

    // ---- mm0+proj0 role: 4 nodes per block, wave = K-quarter.
    const int kq = threadIdx.x >> 6;
    const int r0 = blockIdx.x * 4;

    // stage 4 feat rows (8 KB) with coalesced float4 loads
    {
        const float4* fsrc = reinterpret_cast<const float4*>(feat + (size_t)r0 * FDIM);
        float4* fdst = reinterpret_cast<float4*>(&feat_s[0][0]);
        fdst[threadIdx.x] = fsrc[threadIdx.x];
        fdst[threadIdx.x + 256] = fsrc[threadIdx.x + 256];
    }
    __syncthreads();

    float acc[4] = {0.f, 0.f, 0.f, 0.f};
    const int k0 = kq * (FDIM / 4);
    for (int k = k0; k < k0 + FDIM / 4; k += 8) {
        float w[8];
#pragma unroll
        for (int u = 0; u < 8; u++) w[u] = W0[(k + u) * DH + lane];
#pragma unroll
        for (int r = 0; r < 4; r++) {
            float4 a0 = *reinterpret_cast<const float4*>(&feat_s[r][k]);
            float4 a1 = *reinterpret_cast<const float4*>(&feat_s[r][k + 4]);
            acc[r] = fmaf(a0.x, w[0], fmaf(a0.y, w[1], fmaf(a0.z, w[2], fmaf(a0.w, w[3], acc[r]))));
            acc[r] = fmaf(a1.x, w[4], fmaf(a1.y, w[5], fmaf(a1.z, w[6], fmaf(a1.w, w[7], acc[r]))));
        }
    }
    __syncthreads();
#pragma unroll
    for (int r = 0; r < 4; r++) part[kq][r][lane] = acc[r];
    __syncthreads();

    float xv = part[0][kq][lane] + part[1][kq][lane] + part[2][kq][lane] + part[3][kq][lane];
    const int node = r0 + kq;
    x[(size_t)node * DH + lane] = xv;
#pragma unroll
    for (int hh = 0; hh < 8; hh++) {
        float vl = xv * al0[lane * 8 + hh];
        float vr = xv * ar0[lane * 8 + hh];
#pragma unroll
        for (int off = 32; off >= 1; off >>= 1) {
            vl += __shfl_xor(vl, off, 64);
            vr += __shfl_xor(vr, off, 64);
        }
        if (lane == 0) {
            el[node * 8 + hh] = vl;
            er[node * 8 + hh] = vr;
        }
    }
}

// ---------------------------------------------------------------------------
// Kernel 2/3 (fused agg_L + mm_{L+1} + proj): block = 4 nodes, 256 threads.
// Phase A: two-round pipeline per 16 nbrs (weight round: lane=(nbr,head),
// one expf per (j,h); aggregate round: lane=feature dim, LDS weight tile).
// Phase B: x_out = h_s @ W from LDS, then el/er shuffle projections.
// ---------------------------------------------------------------------------
template <int PROJ_H>
__global__ __launch_bounds__(256) void k_agg_mm(
    const float* __restrict__ x_in, const float* __restrict__ el_in,
    const float* __restrict__ er_in, const int* __restrict__ nbr,
    const int* __restrict__ deg, const float* __restrict__ bias_agg,
    const float* __restrict__ W, const float* __restrict__ al,
    const float* __restrict__ ar, float* __restrict__ x_out,
    float* __restrict__ el_out, float* __restrict__ er_out)
{
    __shared__ float h_s[4][FDIM];     // 8 KB
    __shared__ float part[4][4][DH];   // 4 KB
    __shared__ float w_s[4][16][4];    // 1 KB
    const int lane = threadIdx.x & 63;
    const int wv = threadIdx.x >> 6;   // 0..3
    const int n0 = blockIdx.x * 4;
    const float bv = bias_agg[lane];

    // ---- Phase A: 8 tasks (node x head-half) over 4 waves
    for (int t = wv; t < 8; t += 4) {
        const int node = n0 + (t >> 1);
        const int h0 = (t & 1) * 4;
        const float eli = el_in[node * 8 + h0 + (lane & 3)];
        float acc[4] = {0.f, 0.f, 0.f, 0.f};
        float denp = 0.f;
        const int dg = deg[node];
        const int* nb = nbr + (size_t)node * CAP;

        for (int c0 = 0; c0 < dg; c0 += 16) {
            int jj = c0 + (lane >> 2);
            int jidx = jj < dg ? jj : dg - 1;
            int j = nb[jidx];
            float e = er_in[j * 8 + h0 + (lane & 3)];
            float s = eli + e;
            s = s > 0.f ? s : 0.2f * s;
            float w = (jj < dg) ? __expf(s) : 0.f;
            w_s[wv][lane >> 2][lane & 3] = w;
            denp += w;
#pragma unroll
            for (int k = 0; k < 16; k++) {
                int jk = __shfl(j, 4 * k, 64);
                float4 w4 = *reinterpret_cast<const float4*>(&w_s[wv][k][0]);
                float xv = x_in[(size_t)jk * DH + lane];
                acc[0] = fmaf(w4.x, xv, acc[0]);
                acc[1] = fmaf(w4.y, xv, acc[1]);
                acc[2] = fmaf(w4.z, xv, acc[2]);
                acc[3] = fmaf(w4.w, xv, acc[3]);
            }
        }
        denp += __shfl_xor(denp, 4, 64);
        denp += __shfl_xor(denp, 8, 64);
        denp += __shfl_xor(denp, 16, 64);
        denp += __shfl_xor(denp, 32, 64);
#pragma unroll
        for (int hh = 0; hh < 4; hh++) {
            float den = __shfl(denp, hh, 64);
            float o = acc[hh] / fmaxf(den, 1e-12f) + bv;
            o = o > 0.f ? o : __expf(o) - 1.f;     // elu
            h_s[t >> 1][(h0 + hh) * DH + lane] = o;
        }
    }
    __syncthreads();

    // ---- Phase B: mm + proj from LDS (wave = K-quarter)
    float acc[4] = {0.f, 0.f, 0.f, 0.f};
    const int k0 = wv * (FDIM / 4);
    for (int k = k0; k < k0 + FDIM / 4; k += 8) {
        float w[8];
#pragma unroll
        for (int u = 0; u < 8; u++) w[u] = W[(k + u) * DH + lane];
#pragma unroll
        for (int r = 0; r < 4; r++) {
            float4 a0 = *reinterpret_cast<const float4*>(&h_s[r][k]);
            float4 a1 = *reinterpret_cast<const float4*>(&h_s[r][k + 4]);
            acc[r] = fmaf(a0.x, w[0], fmaf(a0.y, w[1], fmaf(a0.z, w[2], fmaf(a0.w, w[3], acc[r]))));
            acc[r] = fmaf(a1.x, w[4], fmaf(a1.y, w[5], fmaf(a1.z, w[6], fmaf(a1.w, w[7], acc[r]))));
        }
    }
#pragma unroll
    for (int r = 0; r < 4; r++) part[wv][r][lane] = acc[r];
    __syncthreads();

    float xv = part[0][wv][lane] + part[1][wv][lane]
             + part[2][wv][lane] + part[3][wv][lane];
    const int node = n0 + wv;
    x_out[(size_t)node * DH + lane] = xv;
#pragma unroll
    for (int hh = 0; hh < PROJ_H; hh++) {
        float vl = xv * al[lane * PROJ_H + hh];
        float vr = xv * ar[lane * PROJ_H + hh];
#pragma unroll
        for (int off = 32; off >= 1; off >>= 1) {
            vl += __shfl_xor(vl, off, 64);
            vr += __shfl_xor(vr, off, 64);
        }
        if (lane == 0) {
            el_out[node * PROJ_H + hh] = vl;
            er_out[node * PROJ_H + hh] = vr;
        }
    }
}

// ---------------------------------------------------------------------------
// Kernel 4: final aggregate (H=1, no activation) -> d_out.
// ---------------------------------------------------------------------------
__global__ __launch_bounds__(256) void k_agg_final(
    const float* __restrict__ x_in, const float* __restrict__ el_in,
    const float* __restrict__ er_in, const int* __restrict__ nbr,
    const int* __restrict__ deg, const float* __restrict__ bias,
    float* __restrict__ out)
{
    const int node = blockIdx.x * 4 + (threadIdx.x >> 6);
    const int lane = threadIdx.x & 63;
    const float eli = el_in[node];
    float acc = 0.f, denp = 0.f;
    const int dg = deg[node];
    const int* nb = nbr + (size_t)node * CAP;

    for (int c0 = 0; c0 < dg; c0 += 64) {
        int jj = c0 + lane;
        int jidx = jj < dg ? jj : dg - 1;
        int j = nb[jidx];
        float e = er_in[j];
        float s = eli + e;
        s = s > 0.f ? s : 0.2f * s;
        float w = (jj < dg) ? __expf(s) : 0.f;
        denp += w;
        int cnt = dg - c0; cnt = cnt < 64 ? cnt : 64;
#pragma unroll 4
        for (int k = 0; k < cnt; k++) {
            int jk = __shfl(j, k, 64);
            float wk = __shfl(w, k, 64);
            float xv = x_in[(size_t)jk * DH + lane];
            acc = fmaf(wk, xv, acc);
        }
    }
#pragma unroll
    for (int off = 32; off >= 1; off >>= 1) denp += __shfl_xor(denp, off, 64);
    out[(size_t)node * DH + lane] = acc / fmaxf(denp, 1e-12f) + bias[lane];
}

// ---------------------------------------------------------------------------
extern "C" void kernel_launch(void* const* d_in, const int* in_sizes, int n_in,
                              void* d_out, int out_size, void* d_ws, size_t ws_size,
                              hipStream_t stream)
{
    const float* adj  = (const float*)d_in[0];
    const float* feat = (const float*)d_in[1];
    const float* W0   = (const float*)d_in[2];
    const float* al0  = (const float*)d_in[3];
    const float* ar0  = (const float*)d_in[4];
    const float* b0   = (const float*)d_in[5];
    const float* W1   = (const float*)d_in[6];
    const float* al1  = (const float*)d_in[7];
    const float* ar1  = (const float*)d_in[8];
    const float* b1   = (const float*)d_in[9];
    const float* W2   = (const float*)d_in[10];
    const float* al2  = (const float*)d_in[11];
    const float* ar2  = (const float*)d_in[12];
    const float* b2   = (const float*)d_in[13];
    float* out = (float*)d_out;

    char* ws = (char*)d_ws;
    int*   nbr = (int*)ws;   ws += (size_t)NNODES * CAP * sizeof(int);   // 2 MB
    int*   deg = (int*)ws;   ws += (size_t)NNODES * sizeof(int);         // 16 KB
    float* x0  = (float*)ws; ws += (size_t)NNODES * DH * sizeof(float);  // 1 MB
    float* x1  = (float*)ws; ws += (size_t)NNODES * DH * sizeof(float);  // 1 MB
    float* elA = (float*)ws; ws += (size_t)NNODES * 8 * sizeof(float);   // 128 KB
    float* erA = (float*)ws; ws += (size_t)NNODES * 8 * sizeof(float);   // 128 KB
    float* elB = (float*)ws; ws += (size_t)NNODES * 8 * sizeof(float);   // 128 KB
    float* erB = (float*)ws; ws += (size_t)NNODES * 8 * sizeof(float);   // 128 KB

    // K1: layer-0 mm/proj (blocks 0..1023, first) + build (4096 blocks)
    k_mm0_build<<<NNODES / 4 + NNODES, 256, 0, stream>>>(
        adj, nbr, deg, feat, W0, al0, ar0, x0, elA, erA);

    // K2: agg0 + mm1/proj1   (x0,elA,erA -> x1,elB,erB)
    k_agg_mm<8><<<NNODES / 4, 256, 0, stream>>>(
        x0, elA, erA, nbr, deg, b0, W1, al1, ar1, x1, elB, erB);

    // K3: agg1 + mm2/proj2   (x1,elB,erB -> x0,elA,erA; PROJ_H=1)
    k_agg_mm<1><<<NNODES / 4, 256, 0, stream>>>(
        x1, elB, erB, nbr, deg, b1, W2, al2, ar2, x0, elA, erA);

    // K4: final aggregate (H=1, no act) -> out
    k_agg_final<<<NNODES / 4, 256, 0, stream>>>(x0, elA, erA, nbr, deg, b2, out);
}

// Round 8
// 186.755 us; speedup vs baseline: 5.6801x; 1.0141x over previous
//
#include <hip/hip_runtime.h>
#include <cmath>

#define NNODES 4096
#define FDIM 512
#define DH 64
#define CAP 128

// ---------------------------------------------------------------------------
// Kernel 1 (heterogeneous): blocks [0,1024) run layer-0 mm+proj; blocks
// [1024,1024+4096) build neighbor lists (one block per adjacency row).
// mm role: feat rows staged to LDS via coalesced float4 loads.
// build role: ballot-compaction — one LDS atomic per wave per round, empty
// rounds (~70%) skipped with a single uniform branch.
// ---------------------------------------------------------------------------
__global__ __launch_bounds__(256) void k_mm0_build(
    const float* __restrict__ adj, int* __restrict__ nbr, int* __restrict__ deg,
    const float* __restrict__ feat, const float* __restrict__ W0,
    const float* __restrict__ al0, const float* __restrict__ ar0,
    float* __restrict__ x, float* __restrict__ el, float* __restrict__ er)
{
    __shared__ float feat_s[4][FDIM];   // 8 KB (mm role)
    __shared__ float part[4][4][DH];    // 4 KB (mm role)
    __shared__ int cnt;                 // build role
    const int lane = threadIdx.x & 63;

    if (blockIdx.x >= NNODES / 4) {
        const int row = blockIdx.x - NNODES / 4;
        if (threadIdx.x == 0) cnt = 0;
        __syncthreads();
        const float4* arow = reinterpret_cast<const float4*>(adj + (size_t)row * NNODES);
        int* nrow = nbr + (size_t)row * CAP;
        float4 v[4];
        v[0] = arow[threadIdx.x];
        v[1] = arow[threadIdx.x + 256];
        v[2] = arow[threadIdx.x + 512];
        v[3] = arow[threadIdx.x + 768];
        const unsigned long long lmask = (1ull << lane) - 1ull;
#pragma unroll
        for (int s = 0; s < 4; s++) {
            const int colbase = (threadIdx.x + s * 256) * 4;
            float vals[4] = {v[s].x, v[s].y, v[s].z, v[s].w};
#pragma unroll
            for (int e = 0; e < 4; e++) {
                bool nz = vals[e] != 0.f;
                unsigned long long m = __ballot(nz);
                if (m) {
                    int base = 0;
                    if (lane == 0) base = atomicAdd(&cnt, __popcll(m));
                    base = __shfl(base, 0, 64);
                    if (nz) {
                        int idx = base + __popcll(m & lmask);
                        if (idx < CAP) nrow[idx] = colbase + e;
                    }
                }
            }
        }
        __syncthreads();
        if (threadIdx.x == 0) deg[row] = cnt < CAP ? cnt : CAP;
        return;
    }

    // ---- mm0+proj0: 4 nodes per block, wave = K-quarter, feat from LDS
    const int kq = threadIdx.x >> 6;
    const int r0 = blockIdx.x * 4;
    {
        const float4* fsrc = reinterpret_cast<const float4*>(feat + (size_t)r0 * FDIM);
        float4* fdst = reinterpret_cast<float4*>(&feat_s[0][0]);
        fdst[threadIdx.x] = fsrc[threadIdx.x];
        fdst[threadIdx.x + 256] = fsrc[threadIdx.x + 256];
    }
    __syncthreads();

    float acc[4] = {0.f, 0.f, 0.f, 0.f};
    const int k0 = kq * (FDIM / 4);
    for (int k = k0; k < k0 + FDIM / 4; k += 8) {
        float w[8];
#pragma unroll
        for (int u = 0; u < 8; u++) w[u] = W0[(k + u) * DH + lane];
#pragma unroll
        for (int r = 0; r < 4; r++) {
            float4 a0 = *reinterpret_cast<const float4*>(&feat_s[r][k]);
            float4 a1 = *reinterpret_cast<const float4*>(&feat_s[r][k + 4]);
            acc[r] = fmaf(a0.x, w[0], fmaf(a0.y, w[1], fmaf(a0.z, w[2], fmaf(a0.w, w[3], acc[r]))));
            acc[r] = fmaf(a1.x, w[4], fmaf(a1.y, w[5], fmaf(a1.z, w[6], fmaf(a1.w, w[7], acc[r]))));
        }
    }
    __syncthreads();
#pragma unroll
    for (int r = 0; r < 4; r++) part[kq][r][lane] = acc[r];
    __syncthreads();

    float xv = part[0][kq][lane] + part[1][kq][lane] + part[2][kq][lane] + part[3][kq][lane];
    const int node = r0 + kq;
    x[(size_t)node * DH + lane] = xv;
#pragma unroll
    for (int hh = 0; hh < 8; hh++) {
        float vl = xv * al0[lane * 8 + hh];
        float vr = xv * ar0[lane * 8 + hh];
#pragma unroll
        for (int off = 32; off >= 1; off >>= 1) {
            vl += __shfl_xor(vl, off, 64);
            vr += __shfl_xor(vr, off, 64);
        }
        if (lane == 0) {
            el[node * 8 + hh] = vl;
            er[node * 8 + hh] = vr;
        }
    }
}

// ---------------------------------------------------------------------------
// Kernel 2/3 (fused agg_L + mm_{L+1} + proj): block = 4 nodes, 256 threads.
// Phase A: ONE wave-task per node covering all 8 heads (R7 restructure —
//   the old head-half split loaded every neighbor x-row twice).
//   weight round: lane = (nbr 0..7) x (head 0..7), one expf per (j,h),
//     weights -> LDS tile, den accumulated per-lane, one xor-reduce/node.
//   aggregate round: 8 unrolled iters {shfl j, 2x broadcast ds_read_b128
//     (8 head weights), coalesced x load, 8 fma}. Padded lanes carry w=0.
// Phase B: x_out = h_s @ W from LDS (wave = K-quarter), then el/er proj.
// ---------------------------------------------------------------------------
template <int PROJ_H>
__global__ __launch_bounds__(256) void k_agg_mm(
    const float* __restrict__ x_in, const float* __restrict__ el_in,
    const float* __restrict__ er_in, const int* __restrict__ nbr,
    const int* __restrict__ deg, const float* __restrict__ bias_agg,
    const float* __restrict__ W, const float* __restrict__ al,
    const float* __restrict__ ar, float* __restrict__ x_out,
    float* __restrict__ el_out, float* __restrict__ er_out)
{
    __shared__ float h_s[4][FDIM];     // 8 KB
    __shared__ float part[4][4][DH];   // 4 KB
    __shared__ float w_s[4][8][8];     // 1 KB
    const int lane = threadIdx.x & 63;
    const int wv = threadIdx.x >> 6;   // 0..3 = node within block
    const int node = blockIdx.x * 4 + wv;
    const float bv = bias_agg[lane];

    // ---- Phase A: all 8 heads of one node per wave
    {
        const int nl = lane >> 3;      // neighbor slot 0..7
        const int hh = lane & 7;       // head 0..7
        const float eli = el_in[node * 8 + hh];
        float acc[8] = {0.f, 0.f, 0.f, 0.f, 0.f, 0.f, 0.f, 0.f};
        float denp = 0.f;
        const int dg = deg[node];
        const int* nb = nbr + (size_t)node * CAP;

        for (int c0 = 0; c0 < dg; c0 += 8) {
            // weight round: one expf per (neighbor, head)
            int jj = c0 + nl;
            int jidx = jj < dg ? jj : dg - 1;
            int j = nb[jidx];
            float e = er_in[j * 8 + hh];
            float s = eli + e;
            s = s > 0.f ? s : 0.2f * s;
            float w = (jj < dg) ? __expf(s) : 0.f;
            w_s[wv][nl][hh] = w;
            denp += w;
            // aggregate round: lane = feature dim
#pragma unroll
            for (int k = 0; k < 8; k++) {
                int jk = __shfl(j, k * 8, 64);
                float4 wa = *reinterpret_cast<const float4*>(&w_s[wv][k][0]);
                float4 wb = *reinterpret_cast<const float4*>(&w_s[wv][k][4]);
                float xv = x_in[(size_t)jk * DH + lane];
                acc[0] = fmaf(wa.x, xv, acc[0]);
                acc[1] = fmaf(wa.y, xv, acc[1]);
                acc[2] = fmaf(wa.z, xv, acc[2]);
                acc[3] = fmaf(wa.w, xv, acc[3]);
                acc[4] = fmaf(wb.x, xv, acc[4]);
                acc[5] = fmaf(wb.y, xv, acc[5]);
                acc[6] = fmaf(wb.z, xv, acc[6]);
                acc[7] = fmaf(wb.w, xv, acc[7]);
            }
        }
        // reduce den over neighbor-slot lanes (bits 3..5); lane h then holds den[h]
        denp += __shfl_xor(denp, 8, 64);
        denp += __shfl_xor(denp, 16, 64);
        denp += __shfl_xor(denp, 32, 64);
#pragma unroll
        for (int h = 0; h < 8; h++) {
            float den = __shfl(denp, h, 64);
            float o = acc[h] / fmaxf(den, 1e-12f) + bv;
            o = o > 0.f ? o : __expf(o) - 1.f;     // elu
            h_s[wv][h * DH + lane] = o;
        }
    }
    __syncthreads();

    // ---- Phase B: mm + proj from LDS (wave = K-quarter)
    float acc[4] = {0.f, 0.f, 0.f, 0.f};
    const int k0 = wv * (FDIM / 4);
    for (int k = k0; k < k0 + FDIM / 4; k += 8) {
        float w[8];
#pragma unroll
        for (int u = 0; u < 8; u++) w[u] = W[(k + u) * DH + lane];
#pragma unroll
        for (int r = 0; r < 4; r++) {
            float4 a0 = *reinterpret_cast<const float4*>(&h_s[r][k]);
            float4 a1 = *reinterpret_cast<const float4*>(&h_s[r][k + 4]);
            acc[r] = fmaf(a0.x, w[0], fmaf(a0.y, w[1], fmaf(a0.z, w[2], fmaf(a0.w, w[3], acc[r]))));
            acc[r] = fmaf(a1.x, w[4], fmaf(a1.y, w[5], fmaf(a1.z, w[6], fmaf(a1.w, w[7], acc[r]))));
        }
    }
#pragma unroll
    for (int r = 0; r < 4; r++) part[wv][r][lane] = acc[r];
    __syncthreads();

    float xv = part[0][wv][lane] + part[1][wv][lane]
             + part[2][wv][lane] + part[3][wv][lane];
    const int onode = blockIdx.x * 4 + wv;
    x_out[(size_t)onode * DH + lane] = xv;
#pragma unroll
    for (int hh = 0; hh < PROJ_H; hh++) {
        float vl = xv * al[lane * PROJ_H + hh];
        float vr = xv * ar[lane * PROJ_H + hh];
#pragma unroll
        for (int off = 32; off >= 1; off >>= 1) {
            vl += __shfl_xor(vl, off, 64);
            vr += __shfl_xor(vr, off, 64);
        }
        if (lane == 0) {
            el_out[onode * PROJ_H + hh] = vl;
            er_out[onode * PROJ_H + hh] = vr;
        }
    }
}

// ---------------------------------------------------------------------------
// Kernel 4: final aggregate (H=1, no activation) -> d_out.
// ---------------------------------------------------------------------------
__global__ __launch_bounds__(256) void k_agg_final(
    const float* __restrict__ x_in, const float* __restrict__ el_in,
    const float* __restrict__ er_in, const int* __restrict__ nbr,
    const int* __restrict__ deg, const float* __restrict__ bias,
    float* __restrict__ out)
{
    const int node = blockIdx.x * 4 + (threadIdx.x >> 6);
    const int lane = threadIdx.x & 63;
    const float eli = el_in[node];
    float acc = 0.f, denp = 0.f;
    const int dg = deg[node];
    const int* nb = nbr + (size_t)node * CAP;

    for (int c0 = 0; c0 < dg; c0 += 64) {
        int jj = c0 + lane;
        int jidx = jj < dg ? jj : dg - 1;
        int j = nb[jidx];
        float e = er_in[j];
        float s = eli + e;
        s = s > 0.f ? s : 0.2f * s;
        float w = (jj < dg) ? __expf(s) : 0.f;
        denp += w;
        int cnt = dg - c0; cnt = cnt < 64 ? cnt : 64;
#pragma unroll 4
        for (int k = 0; k < cnt; k++) {
            int jk = __shfl(j, k, 64);
            float wk = __shfl(w, k, 64);
            float xv = x_in[(size_t)jk * DH + lane];
            acc = fmaf(wk, xv, acc);
        }
    }
#pragma unroll
    for (int off = 32; off >= 1; off >>= 1) denp += __shfl_xor(denp, off, 64);
    out[(size_t)node * DH + lane] = acc / fmaxf(denp, 1e-12f) + bias[lane];
}

// ---------------------------------------------------------------------------
extern "C" void kernel_launch(void* const* d_in, const int* in_sizes, int n_in,
                              void* d_out, int out_size, void* d_ws, size_t ws_size,
                              hipStream_t stream)
{
    const float* adj  = (const float*)d_in[0];
    const float* feat = (const float*)d_in[1];
    const float* W0   = (const float*)d_in[2];
    const float* al0  = (const float*)d_in[3];
    const float* ar0  = (const float*)d_in[4];
    const float* b0   = (const float*)d_in[5];
    const float* W1   = (const float*)d_in[6];
    const float* al1  = (const float*)d_in[7];
    const float* ar1  = (const float*)d_in[8];
    const float* b1   = (const float*)d_in[9];
    const float* W2   = (const float*)d_in[10];
    const float* al2  = (const float*)d_in[11];
    const float* ar2  = (const float*)d_in[12];
    const float* b2   = (const float*)d_in[13];
    float* out = (float*)d_out;

    char* ws = (char*)d_ws;
    int*   nbr = (int*)ws;   ws += (size_t)NNODES * CAP * sizeof(int);   // 2 MB
    int*   deg = (int*)ws;   ws += (size_t)NNODES * sizeof(int);         // 16 KB
    float* x0  = (float*)ws; ws += (size_t)NNODES * DH * sizeof(float);  // 1 MB
    float* x1  = (float*)ws; ws += (size_t)NNODES * DH * sizeof(float);  // 1 MB
    float* elA = (float*)ws; ws += (size_t)NNODES * 8 * sizeof(float);   // 128 KB
    float* erA = (float*)ws; ws += (size_t)NNODES * 8 * sizeof(float);   // 128 KB
    float* elB = (float*)ws; ws += (size_t)NNODES * 8 * sizeof(float);   // 128 KB
    float* erB = (float*)ws; ws += (size_t)NNODES * 8 * sizeof(float);   // 128 KB

    // K1: layer-0 mm/proj (blocks 0..1023, first) + build (4096 blocks)
    k_mm0_build<<<NNODES / 4 + NNODES, 256, 0, stream>>>(
        adj, nbr, deg, feat, W0, al0, ar0, x0, elA, erA);

    // K2: agg0 + mm1/proj1   (x0,elA,erA -> x1,elB,erB)
    k_agg_mm<8><<<NNODES / 4, 256, 0, stream>>>(
        x0, elA, erA, nbr, deg, b0, W1, al1, ar1, x1, elB, erB);

    // K3: agg1 + mm2/proj2   (x1,elB,erB -> x0,elA,erA; PROJ_H=1)
    k_agg_mm<1><<<NNODES / 4, 256, 0, stream>>>(
        x1, elB, erB, nbr, deg, b1, W2, al2, ar2, x0, elA, erA);

    // K4: final aggregate (H=1, no act) -> out
    k_agg_final<<<NNODES / 4, 256, 0, stream>>>(x0, elA, erA, nbr, deg, b2, out);
}